// Round 1
// baseline (3125.195 us; speedup 1.0000x reference)
//
#include <hip/hip_runtime.h>

#define Bn 256
#define Tn 2048
#define Dn 40
#define Hn 128
#define Cn 35

typedef _Float16 h2 __attribute__((ext_vector_type(2)));

__device__ __forceinline__ float fdot2f(h2 a, h2 b, float c) {
#if __has_builtin(__builtin_amdgcn_fdot2)
  return __builtin_amdgcn_fdot2(a, b, c, false);
#else
  return c + (float)(a[0]) * (float)(b[0]) + (float)(a[1]) * (float)(b[1]);
#endif
}

__device__ __forceinline__ h2 pk2(float a, float b) {
  h2 r; r[0] = (_Float16)a; r[1] = (_Float16)b; return r;
}

__device__ __forceinline__ float rcpf_(float x) {
#if __has_builtin(__builtin_amdgcn_rcpf)
  return __builtin_amdgcn_rcpf(x);
#else
  return 1.f / x;
#endif
}

__device__ __forceinline__ float sigm(float v) {
  v = fmaxf(fminf(v, 60.f), -60.f);
  return rcpf_(1.f + __expf(-v));
}

__device__ __forceinline__ float tanha(float v) {
  v = fmaxf(fminf(v, 15.f), -15.f);
  const float e = __expf(2.f * v);
  return (e - 1.f) * rcpf_(e + 1.f);
}

struct H8u { h2 p[4]; };
// 16B LDS load of 4 f16-pairs starting at pair index 4*idx4 (base 16B-aligned)
__device__ __forceinline__ H8u ld8(const h2* base, int idx4) {
  const uint4 u = reinterpret_cast<const uint4*>(base)[idx4];
  H8u r;
  r.p[0] = __builtin_bit_cast(h2, u.x);
  r.p[1] = __builtin_bit_cast(h2, u.y);
  r.p[2] = __builtin_bit_cast(h2, u.z);
  r.p[3] = __builtin_bit_cast(h2, u.w);
  return r;
}

// One workgroup per batch element. 512 threads; thread tid owns gate column
// tid of layer 0 AND gate column tid of layer 1. All weights register-resident
// as packed f16 pairs (212 VGPRs/thread). dot2 f16 with f32 accumulate.
// Per step: P1 (L0 gates) | barrier | P2 (L0 update thr 0-127, L1 update of
// PREVIOUS step's gates thr 128-255, concurrently) | barrier | P3 (L1 gates)
// | barrier. L1 update pipelined one step behind; epilogue applies the last.
__global__ __launch_bounds__(512, 2) void lstm2_fused(
    const float* __restrict__ x,
    const int*   __restrict__ length,
    const float* __restrict__ Wih0, const float* __restrict__ Whh0,
    const float* __restrict__ bih0, const float* __restrict__ bhh0,
    const float* __restrict__ Wih1, const float* __restrict__ Whh1,
    const float* __restrict__ bih1, const float* __restrict__ bhh1,
    const float* __restrict__ gam,  const float* __restrict__ bet,
    const float* __restrict__ fcw,  const float* __restrict__ fcb,
    float* __restrict__ out)
{
  __shared__ __align__(16) h2 s_x[16 * 24];   // 16-step x chunk, row stride 24 pairs (96B, keeps rows 16B-aligned)
  __shared__ __align__(16) h2 s_h0[64];       // h0 as 64 f16 pairs
  __shared__ __align__(16) h2 s_h1[64];       // h1 as 64 f16 pairs
  __shared__ float s_g0[512];
  __shared__ float s_g1[512];
  __shared__ float s_h1f[128];
  __shared__ float s_hn[128];

  const int tid = threadIdx.x;
  const int b   = blockIdx.x;
  const int len = length[b];   // 1..2048 guaranteed

  // ---- register-resident weights (packed f16 pairs) ----
  h2 w0x[20]; h2 w0h[64]; h2 w1x[64]; h2 w1h[64];
  {
    const float* p = Wih0 + tid * Dn;
#pragma unroll
    for (int j = 0; j < 20; ++j) w0x[j] = pk2(p[2 * j], p[2 * j + 1]);
  }
  {
    const float* p = Whh0 + tid * Hn;
#pragma unroll
    for (int j = 0; j < 64; ++j) w0h[j] = pk2(p[2 * j], p[2 * j + 1]);
  }
  {
    const float* p = Wih1 + tid * Hn;
#pragma unroll
    for (int j = 0; j < 64; ++j) w1x[j] = pk2(p[2 * j], p[2 * j + 1]);
  }
  {
    const float* p = Whh1 + tid * Hn;
#pragma unroll
    for (int j = 0; j < 64; ++j) w1h[j] = pk2(p[2 * j], p[2 * j + 1]);
  }
  const float bias0 = bih0[tid] + bhh0[tid];
  const float bias1 = bih1[tid] + bhh1[tid];

  float c0 = 0.f;  // valid on threads 0..127   (L0 unit tid)
  float c1 = 0.f;  // valid on threads 128..255 (L1 unit tid-128)

  if (tid < 64) {
    h2 z; z[0] = (_Float16)0.f; z[1] = (_Float16)0.f;
    s_h0[tid] = z; s_h1[tid] = z;
  }
  __syncthreads();

#pragma unroll 1
  for (int t = 0; t < len; ++t) {
    const int tl = t & 15;
    if (tl == 0) {
      // stage x[b, t..t+15, :] as f16 pairs (t<=2032 always, so in-bounds)
      if (tid < 320) {
        const int r = tid / 20, k = tid - r * 20;
        const float2 xv = *reinterpret_cast<const float2*>(
            x + ((size_t)b * Tn + (size_t)(t + r)) * Dn + 2 * k);
        s_x[r * 24 + k] = pk2(xv.x, xv.y);
      }
      __syncthreads();
    }

    // ---- P1: layer-0 gates (reads s_h0 = state t-1, s_x) ----
    {
      float acc = bias0, acc2 = 0.f;
      const h2* xr = s_x + tl * 24;
#pragma unroll
      for (int j = 0; j < 5; ++j) {
        const H8u v = ld8(xr, j);
        acc  = fdot2f(v.p[0], w0x[4 * j + 0], acc);
        acc2 = fdot2f(v.p[1], w0x[4 * j + 1], acc2);
        acc  = fdot2f(v.p[2], w0x[4 * j + 2], acc);
        acc2 = fdot2f(v.p[3], w0x[4 * j + 3], acc2);
      }
#pragma unroll
      for (int j = 0; j < 16; ++j) {
        const H8u v = ld8(s_h0, j);
        acc  = fdot2f(v.p[0], w0h[4 * j + 0], acc);
        acc2 = fdot2f(v.p[1], w0h[4 * j + 1], acc2);
        acc  = fdot2f(v.p[2], w0h[4 * j + 2], acc);
        acc2 = fdot2f(v.p[3], w0h[4 * j + 3], acc2);
      }
      s_g0[tid] = acc + acc2;
    }
    __syncthreads();  // A: s_g0 ready

    // ---- P2: cell updates (L0 now; L1 applies previous step's g1) ----
    if (tid < 128) {
      const float gi = s_g0[tid], gf = s_g0[Hn + tid];
      const float gg = s_g0[2 * Hn + tid], go = s_g0[3 * Hn + tid];
      const float fi = sigm(gi), ff = sigm(gf), fg = tanha(gg), fo = sigm(go);
      c0 = ff * c0 + fi * fg;
      reinterpret_cast<_Float16*>(s_h0)[tid] = (_Float16)(fo * tanha(c0));
    } else if (tid < 256 && t > 0) {
      const int u = tid - 128;
      const float gi = s_g1[u], gf = s_g1[Hn + u];
      const float gg = s_g1[2 * Hn + u], go = s_g1[3 * Hn + u];
      const float fi = sigm(gi), ff = sigm(gf), fg = tanha(gg), fo = sigm(go);
      c1 = ff * c1 + fi * fg;
      reinterpret_cast<_Float16*>(s_h1)[u] = (_Float16)(fo * tanha(c1));
    }
    __syncthreads();  // B: s_h0 (state t), s_h1 (state t-1) ready

    // ---- P3: layer-1 gates (reads new s_h0, s_h1) ----
    {
      float acc = bias1, acc2 = 0.f;
#pragma unroll
      for (int j = 0; j < 16; ++j) {
        const H8u v = ld8(s_h0, j);
        acc  = fdot2f(v.p[0], w1x[4 * j + 0], acc);
        acc2 = fdot2f(v.p[1], w1x[4 * j + 1], acc2);
        acc  = fdot2f(v.p[2], w1x[4 * j + 2], acc);
        acc2 = fdot2f(v.p[3], w1x[4 * j + 3], acc2);
      }
#pragma unroll
      for (int j = 0; j < 16; ++j) {
        const H8u v = ld8(s_h1, j);
        acc  = fdot2f(v.p[0], w1h[4 * j + 0], acc);
        acc2 = fdot2f(v.p[1], w1h[4 * j + 1], acc2);
        acc  = fdot2f(v.p[2], w1h[4 * j + 2], acc);
        acc2 = fdot2f(v.p[3], w1h[4 * j + 3], acc2);
      }
      s_g1[tid] = acc + acc2;
    }
    __syncthreads();  // C: s_g1 ready for next step's P2 (or epilogue)
  }

  // ---- epilogue: apply the final g1 -> h1 at t = len-1 (fp32) ----
  if (tid >= 128 && tid < 256) {
    const int u = tid - 128;
    const float gi = s_g1[u], gf = s_g1[Hn + u];
    const float gg = s_g1[2 * Hn + u], go = s_g1[3 * Hn + u];
    const float fi = sigm(gi), ff = sigm(gf), fg = tanha(gg), fo = sigm(go);
    c1 = ff * c1 + fi * fg;
    s_h1f[u] = fo * tanha(c1);
  }
  __syncthreads();

  // ---- LayerNorm over H on wave 0 ----
  if (tid < 64) {
    const float a = s_h1f[tid], d = s_h1f[64 + tid];
    float s = a + d, q = a * a + d * d;
#pragma unroll
    for (int m = 32; m >= 1; m >>= 1) {
      s += __shfl_xor(s, m, 64);
      q += __shfl_xor(q, m, 64);
    }
    const float mu = s * (1.f / 128.f);
    float var = q * (1.f / 128.f) - mu * mu;
    var = fmaxf(var, 0.f);
    const float rstd = rsqrtf(var + 1e-5f);
    s_hn[tid]      = (a - mu) * rstd * gam[tid]      + bet[tid];
    s_hn[64 + tid] = (d - mu) * rstd * gam[64 + tid] + bet[64 + tid];
  }
  __syncthreads();

  // ---- FC head: out[b, c] = hn . fc_w[c, :] + fc_b[c] ----
  if (tid < Cn) {
    float acc = fcb[tid];
    const float* wp = fcw + tid * Hn;
#pragma unroll 4
    for (int k = 0; k < Hn; ++k) acc += s_hn[k] * wp[k];
    out[(size_t)b * Cn + tid] = acc;
  }
}

extern "C" void kernel_launch(void* const* d_in, const int* in_sizes, int n_in,
                              void* d_out, int out_size, void* d_ws, size_t ws_size,
                              hipStream_t stream) {
  (void)in_sizes; (void)n_in; (void)d_ws; (void)ws_size; (void)out_size;
  lstm2_fused<<<dim3(Bn), dim3(512), 0, stream>>>(
      (const float*)d_in[0],  (const int*)d_in[1],
      (const float*)d_in[2],  (const float*)d_in[3],
      (const float*)d_in[4],  (const float*)d_in[5],
      (const float*)d_in[6],  (const float*)d_in[7],
      (const float*)d_in[8],  (const float*)d_in[9],
      (const float*)d_in[10], (const float*)d_in[11],
      (const float*)d_in[12], (const float*)d_in[13],
      (float*)d_out);
}